// Round 1
// baseline (112.589 us; speedup 1.0000x reference)
//
#include <hip/hip_runtime.h>
#include <hip/hip_bf16.h>
#include <math.h>

#define B 512
#define M 24
#define F 128
#define NRBF 20
#define CUTOFF 5.0f
#define NPAIR (M * M)   // 576

// One block per molecule. 512 threads.
// Phase 0: load s (emb gather), positions, bf into LDS.
// Phase G: pairwise geometry (d, mask, rhat) + RBF table into LDS.
// Phase 1: h = silu(s @ W1 + b1)           (GEMM over LDS s, global W1)
// Phase 2: phi = h @ W2 (cols 0:F and 2F:3F) + b2  -> sPhi0, sPhi2
// Phase 3: edge aggregation:
//   ds_i[f]   = sum_j mask * (bf0[f] + rbf_ij . Wf0[:,f]) * phi0_j[f]
//   dv_i[f,c] = sum_j mask * (bf2[f] + rbf_ij . Wf2[:,f]) * phi2_j[f] * rhat_ij[c]
// out[node][0:128] = s + ds ; out[node][128+3f+c] = dv[f][c]
// (the dv_v * v term of the reference is identically zero since v^0 = 0)

__global__ __launch_bounds__(512) void painn_kernel(
    const int* __restrict__ atoms,
    const float* __restrict__ apos,
    const float* __restrict__ emb,
    const float* __restrict__ W1, const float* __restrict__ b1,
    const float* __restrict__ W2, const float* __restrict__ b2,
    const float* __restrict__ Wf, const float* __restrict__ bf,
    float* __restrict__ out)
{
    __shared__ __attribute__((aligned(16))) float sSH[M][F];     // s, later h
    __shared__ __attribute__((aligned(16))) float sPhi0[M][F];
    __shared__ __attribute__((aligned(16))) float sPhi2[M][F];
    __shared__ __attribute__((aligned(16))) float sRbf[NPAIR][NRBF];
    __shared__ __attribute__((aligned(16))) float4 sGeo[NPAIR];  // rhat.xyz, mask
    __shared__ __attribute__((aligned(16))) float sPos[M][4];
    __shared__ __attribute__((aligned(16))) float sBf[2 * F];    // bf[0:128] | bf[256:384]

    const int tid = threadIdx.x;
    const int b = blockIdx.x;

    // ---- Phase 0: loads -------------------------------------------------
    // s embeddings: 24 nodes x 128 f = 768 float4
    for (int idx = tid; idx < M * (F / 4); idx += 512) {
        int node = idx >> 5;          // /32
        int f4   = idx & 31;
        int a = atoms[b * M + node];
        float4 v = reinterpret_cast<const float4*>(emb + (size_t)a * F)[f4];
        reinterpret_cast<float4*>(&sSH[node][0])[f4] = v;
    }
    if (tid < M * 3) {
        sPos[tid / 3][tid % 3] = apos[(size_t)b * M * 3 + tid];
    }
    if (tid >= 256 && tid < 512) {
        int t = tid - 256;
        sBf[t] = bf[t < F ? t : t + F];   // t<128 -> bf[t]; else bf[256+(t-128)]
    }
    __syncthreads();

    // ---- Phase G: geometry + RBF ---------------------------------------
    for (int p = tid; p < NPAIR; p += 512) {
        int i = p / M;
        int j = p - i * M;
        float dx = sPos[i][0] - sPos[j][0];
        float dy = sPos[i][1] - sPos[j][1];
        float dz = sPos[i][2] - sPos[j][2];
        float d2 = dx * dx + dy * dy + dz * dz;
        float d = sqrtf(d2);
        bool m = (d < CUTOFF) && (i != j);
        if (m) {
            float inv = 1.0f / d;
            sGeo[p] = make_float4(dx * inv, dy * inv, dz * inv, 1.0f);
            const float k = 3.14159265358979323846f / CUTOFF;
#pragma unroll
            for (int n = 0; n < NRBF; ++n) {
                sRbf[p][n] = sinf((float)(n + 1) * k * d) * inv;
            }
        } else {
            sGeo[p] = make_float4(0.f, 0.f, 0.f, 0.f);
        }
    }

    // ---- Phase 1: h = silu(s @ W1 + b1) --------------------------------
    // thread: k = tid&127, q = tid>>7 -> nodes q*6 .. q*6+5
    {
        const int k = tid & 127;
        const int q = tid >> 7;
        float acc[6];
#pragma unroll
        for (int t = 0; t < 6; ++t) acc[t] = 0.f;
        for (int f = 0; f < F; ++f) {
            float w = W1[(size_t)f * F + k];
#pragma unroll
            for (int t = 0; t < 6; ++t) acc[t] += sSH[q * 6 + t][f] * w;
        }
        float bk = b1[k];
        float h[6];
#pragma unroll
        for (int t = 0; t < 6; ++t) {
            float x = acc[t] + bk;
            h[t] = x / (1.0f + expf(-x));
        }
        __syncthreads();   // all reads of sSH (s) done; geo writes visible too
#pragma unroll
        for (int t = 0; t < 6; ++t) sSH[q * 6 + t][k] = h[t];
    }
    __syncthreads();

    // ---- Phase 2: phi chunks 0 and 2 -----------------------------------
    // thread: c2 = tid&255 (0..255), hh = tid>>8 -> nodes hh*12 .. hh*12+11
    {
        const int c2 = tid & 255;
        const int hh = tid >> 8;
        const int wcol = (c2 < F) ? c2 : (c2 + F);   // W2 col in [0,384)
        float acc[12];
#pragma unroll
        for (int t = 0; t < 12; ++t) acc[t] = 0.f;
        for (int f = 0; f < F; ++f) {
            float w = W2[(size_t)f * (3 * F) + wcol];
#pragma unroll
            for (int t = 0; t < 12; ++t) acc[t] += sSH[hh * 12 + t][f] * w;
        }
        float bb = b2[wcol];
        if (c2 < F) {
#pragma unroll
            for (int t = 0; t < 12; ++t) sPhi0[hh * 12 + t][c2] = acc[t] + bb;
        } else {
#pragma unroll
            for (int t = 0; t < 12; ++t) sPhi2[hh * 12 + t][c2 - F] = acc[t] + bb;
        }
    }
    __syncthreads();

    // ---- Phase 3: edge aggregation -------------------------------------
    const int f = tid & 127;
    const int iq = tid >> 7;    // 0..3

    // filter weights for this f, loop-invariant -> registers
    float wf0[NRBF], wf2[NRBF];
#pragma unroll
    for (int n = 0; n < NRBF; ++n) {
        wf0[n] = Wf[(size_t)n * (3 * F) + f];
        wf2[n] = Wf[(size_t)n * (3 * F) + 2 * F + f];
    }
    const float bf0 = sBf[f];
    const float bf2 = sBf[F + f];

    for (int ii = 0; ii < 6; ++ii) {
        const int i = iq * 6 + ii;
        float ds = 0.f, dvx = 0.f, dvy = 0.f, dvz = 0.f;
        const int pb = i * M;
        for (int j = 0; j < M; ++j) {
            float4 g = sGeo[pb + j];
            if (g.w != 0.0f) {
                float w0 = bf0, w2 = bf2;
                const float4* rb = reinterpret_cast<const float4*>(&sRbf[pb + j][0]);
#pragma unroll
                for (int q = 0; q < 5; ++q) {
                    float4 r = rb[q];
                    w0 += r.x * wf0[4 * q + 0] + r.y * wf0[4 * q + 1]
                        + r.z * wf0[4 * q + 2] + r.w * wf0[4 * q + 3];
                    w2 += r.x * wf2[4 * q + 0] + r.y * wf2[4 * q + 1]
                        + r.z * wf2[4 * q + 2] + r.w * wf2[4 * q + 3];
                }
                float m0 = w0 * sPhi0[j][f];
                float m2 = w2 * sPhi2[j][f];
                ds  += m0;
                dvx += m2 * g.x;
                dvy += m2 * g.y;
                dvz += m2 * g.z;
            }
        }
        const int node = b * M + i;
        const int a = atoms[node];
        float* o = out + (size_t)node * (4 * F);
        o[f] = emb[(size_t)a * F + f] + ds;
        o[F + 3 * f + 0] = dvx;
        o[F + 3 * f + 1] = dvy;
        o[F + 3 * f + 2] = dvz;
    }
}

extern "C" void kernel_launch(void* const* d_in, const int* in_sizes, int n_in,
                              void* d_out, int out_size, void* d_ws, size_t ws_size,
                              hipStream_t stream) {
    const int*   atoms = (const int*)d_in[0];
    const float* apos  = (const float*)d_in[1];
    // d_in[2] = graph_indexes (unused; batch structure is the fixed [B,M] layout)
    const float* emb = (const float*)d_in[3];
    const float* W1  = (const float*)d_in[4];
    const float* b1  = (const float*)d_in[5];
    const float* W2  = (const float*)d_in[6];
    const float* b2  = (const float*)d_in[7];
    const float* Wf  = (const float*)d_in[8];
    const float* bf  = (const float*)d_in[9];
    float* out = (float*)d_out;

    painn_kernel<<<B, 512, 0, stream>>>(atoms, apos, emb, W1, b1, W2, b2, Wf, bf, out);
}

// Round 2
// 109.959 us; speedup vs baseline: 1.0239x; 1.0239x over previous
//
#include <hip/hip_runtime.h>
#include <hip/hip_bf16.h>
#include <math.h>

#define B 512
#define M 24
#define F 128
#define NRBF 20
#define CUTOFF 5.0f
#define NPAIR (M * M)   // 576

// One block per molecule, 512 threads, 2 blocks/CU (entire grid resident).
// RBF values are NOT stored; per pair we store (r1, r2, c2) and rebuild
// r_n = sin(n*k*d)/d via two parallel Chebyshev recurrences
//   r_{n+2} = c2 * r_n - r_{n-2},  c2 = 2*cos(2*k*d)
// (odd chain seeded r1, r3 = c2*r1 + r1; even chain r2, r4 = c2*r2).
// The dv_v * v term of the reference is identically zero since v^0 = 0.

__global__ __launch_bounds__(512) void painn_kernel(
    const int* __restrict__ atoms,
    const float* __restrict__ apos,
    const float* __restrict__ emb,
    const float* __restrict__ W1, const float* __restrict__ b1,
    const float* __restrict__ W2, const float* __restrict__ b2,
    const float* __restrict__ Wf, const float* __restrict__ bf,
    float* __restrict__ out)
{
    __shared__ __attribute__((aligned(16))) float sSH[M][F];        // s, later h
    __shared__ __attribute__((aligned(16))) float sPhi[M][F][2];    // (phi0, phi2) interleaved
    __shared__ __attribute__((aligned(16))) float4 sGeo[NPAIR];     // rhat.xyz, mask
    __shared__ __attribute__((aligned(16))) float4 sTrig[NPAIR];    // r1, r2, c2, 0
    __shared__ __attribute__((aligned(16))) float sPos[M][4];
    __shared__ __attribute__((aligned(16))) float sBf[2 * F];       // bf[0:128] | bf[256:384]

    const int tid = threadIdx.x;
    const int b = blockIdx.x;

    // ---- Phase 0: loads -------------------------------------------------
    for (int idx = tid; idx < M * (F / 4); idx += 512) {
        int node = idx >> 5;
        int f4   = idx & 31;
        int a = atoms[b * M + node];
        float4 v = reinterpret_cast<const float4*>(emb + (size_t)a * F)[f4];
        reinterpret_cast<float4*>(&sSH[node][0])[f4] = v;
    }
    if (tid < M * 3) {
        sPos[tid / 3][tid % 3] = apos[(size_t)b * M * 3 + tid];
    }
    if (tid >= 256 && tid < 512) {
        int t = tid - 256;
        sBf[t] = bf[t < F ? t : t + F];
    }
    __syncthreads();

    // ---- Phase G: geometry + trig seeds --------------------------------
    for (int p = tid; p < NPAIR; p += 512) {
        int i = p / M;
        int j = p - i * M;
        float dx = sPos[i][0] - sPos[j][0];
        float dy = sPos[i][1] - sPos[j][1];
        float dz = sPos[i][2] - sPos[j][2];
        float d = sqrtf(dx * dx + dy * dy + dz * dz);
        bool m = (d < CUTOFF) && (i != j);
        if (m) {
            float inv = 1.0f / d;
            sGeo[p] = make_float4(dx * inv, dy * inv, dz * inv, 1.0f);
            const float k = 3.14159265358979323846f / CUTOFF;
            float s1, c1;
            __sincosf(k * d, &s1, &c1);
            float r1 = s1 * inv;
            float r2 = 2.0f * s1 * c1 * inv;            // sin(2kd)/d
            float c2 = 2.0f * (2.0f * c1 * c1 - 1.0f);  // 2*cos(2kd)
            sTrig[p] = make_float4(r1, r2, c2, 0.0f);
        } else {
            sGeo[p] = make_float4(0.f, 0.f, 0.f, 0.f);
        }
    }

    // ---- Phase 1: h = silu(s @ W1 + b1) --------------------------------
    {
        const int k = tid & 127;
        const int q = tid >> 7;
        float acc[6];
#pragma unroll
        for (int t = 0; t < 6; ++t) acc[t] = 0.f;
#pragma unroll 4
        for (int f = 0; f < F; ++f) {
            float w = W1[(size_t)f * F + k];
#pragma unroll
            for (int t = 0; t < 6; ++t) acc[t] += sSH[q * 6 + t][f] * w;
        }
        float bk = b1[k];
        float h[6];
#pragma unroll
        for (int t = 0; t < 6; ++t) {
            float x = acc[t] + bk;
            h[t] = x / (1.0f + expf(-x));
        }
        __syncthreads();   // s reads done; geo/trig writes also become visible
#pragma unroll
        for (int t = 0; t < 6; ++t) sSH[q * 6 + t][k] = h[t];
    }
    __syncthreads();

    // ---- Phase 2: phi chunks 0 and 2 -> sPhi[node][f][{0,1}] -----------
    {
        const int c2 = tid & 255;
        const int hh = tid >> 8;
        const int wcol = (c2 < F) ? c2 : (c2 + F);
        float acc[12];
#pragma unroll
        for (int t = 0; t < 12; ++t) acc[t] = 0.f;
#pragma unroll 4
        for (int f = 0; f < F; ++f) {
            float w = W2[(size_t)f * (3 * F) + wcol];
#pragma unroll
            for (int t = 0; t < 12; ++t) acc[t] += sSH[hh * 12 + t][f] * w;
        }
        float bb = b2[wcol];
        const int fcol = (c2 < F) ? c2 : (c2 - F);
        const int lane = (c2 < F) ? 0 : 1;
#pragma unroll
        for (int t = 0; t < 12; ++t) sPhi[hh * 12 + t][fcol][lane] = acc[t] + bb;
    }
    __syncthreads();

    // ---- Phase 3: edge aggregation -------------------------------------
    const int f = tid & 127;
    const int iq = tid >> 7;    // 0..3

    float wf0[NRBF], wf2[NRBF];
#pragma unroll
    for (int n = 0; n < NRBF; ++n) {
        wf0[n] = Wf[(size_t)n * (3 * F) + f];
        wf2[n] = Wf[(size_t)n * (3 * F) + 2 * F + f];
    }
    const float bf0 = sBf[f];
    const float bf2 = sBf[F + f];

    for (int ii = 0; ii < 6; ++ii) {
        const int i = iq * 6 + ii;
        float ds = 0.f, dvx = 0.f, dvy = 0.f, dvz = 0.f;
        const int pb = i * M;
        for (int j = 0; j < M; ++j) {
            float4 g = sGeo[pb + j];
            if (g.w != 0.0f) {                 // wave-uniform branch
                float4 t = sTrig[pb + j];
                float a0 = t.x, b0 = t.y, c2 = t.z;
                // n=1 (a0->wf[0]) and n=2 (b0->wf[1])
                float w0 = bf0 + a0 * wf0[0] + b0 * wf0[1];
                float w2 = bf2 + a0 * wf2[0] + b0 * wf2[1];
                // n=3: sin3x = 2cos2x*sinx + sinx ; n=4: sin4x = 2cos2x*sin2x
                float a1 = c2 * a0 + a0;
                float b1 = c2 * b0;
                w0 += a1 * wf0[2] + b1 * wf0[3];
                w2 += a1 * wf2[2] + b1 * wf2[3];
#pragma unroll
                for (int n = 2; n < 10; ++n) {
                    float a2 = c2 * a1 - a0;   // odd chain:  r_{2n+1}
                    float b2 = c2 * b1 - b0;   // even chain: r_{2n+2}
                    w0 += a2 * wf0[2 * n] + b2 * wf0[2 * n + 1];
                    w2 += a2 * wf2[2 * n] + b2 * wf2[2 * n + 1];
                    a0 = a1; a1 = a2; b0 = b1; b1 = b2;
                }
                float2 ph = *reinterpret_cast<const float2*>(&sPhi[j][f][0]);
                ds  += w0 * ph.x;
                float m2 = w2 * ph.y;
                dvx += m2 * g.x;
                dvy += m2 * g.y;
                dvz += m2 * g.z;
            }
        }
        const int node = b * M + i;
        const int a = atoms[node];
        float* o = out + (size_t)node * (4 * F);
        o[f] = emb[(size_t)a * F + f] + ds;
        o[F + 3 * f + 0] = dvx;
        o[F + 3 * f + 1] = dvy;
        o[F + 3 * f + 2] = dvz;
    }
}

extern "C" void kernel_launch(void* const* d_in, const int* in_sizes, int n_in,
                              void* d_out, int out_size, void* d_ws, size_t ws_size,
                              hipStream_t stream) {
    const int*   atoms = (const int*)d_in[0];
    const float* apos  = (const float*)d_in[1];
    // d_in[2] = graph_indexes (unused; batch structure is the fixed [B,M] layout)
    const float* emb = (const float*)d_in[3];
    const float* W1  = (const float*)d_in[4];
    const float* b1  = (const float*)d_in[5];
    const float* W2  = (const float*)d_in[6];
    const float* b2  = (const float*)d_in[7];
    const float* Wf  = (const float*)d_in[8];
    const float* bf  = (const float*)d_in[9];
    float* out = (float*)d_out;

    painn_kernel<<<B, 512, 0, stream>>>(atoms, apos, emb, W1, b1, W2, b2, Wf, bf, out);
}